// Round 6
// baseline (248.174 us; speedup 1.0000x reference)
//
#include <hip/hip_runtime.h>

// ---- problem constants -----------------------------------------------------
#define IN_DIM   1024
#define OUT_DIM  1024
#define BATCH    4096
#define NC       8        // N_COEFFS
#define NK       12       // N_KNOTS
#define KSPLINE  (IN_DIM * NC)      // 8192
#define KDIM     (KSPLINE + IN_DIM) // 9216
#define EPS      1e-8f

#define NBLK_A   ((IN_DIM / 256) * (BATCH / 16))      // 1024 A-builder blocks
#define NBLK_W   ((OUT_DIM * (KDIM / 4)) / 256)       // 9216 W-builder blocks

// ---- gemm geometry: 256x256 tile, wave-tile 128x64, KSPLIT=4 ---------------
// R0-R5 post-mortem: every schedule fits t = LDS_cyc + MFMA_cyc + ovh (sum,
// no overlap), so the lever is the read:MFMA RATIO = wave-tile area/perimeter.
// 256x256 with 8 waves (2Mx4N) gives wave-tile 128x64: 12 b128-reads / 32 MFMA
// per K32-tile (m201's exact balance: LDS 1152 vs MFMA 1242 cyc/CU/tile) and
// minimizes total per-CU LDS traffic (prop. 1/BM + 1/BN). Structure otherwise
// IDENTICAL to R4's proven ring (4-slot, stage-3-ahead, counted vmcnt).
#define BM       256
#define BN       256
#define BKQ      32
#define KSPLIT   4
#define KPS      (KDIM / KSPLIT)               // 2304
#define NKT      (KPS / BKQ)                   // 72 K-tiles per block
#define NGBLK    ((BATCH / BM) * (OUT_DIM / BN) * KSPLIT)  // 16*4*4 = 256

// LDS row = 32 halfs = 64 B = 4 x 16B chunks. Read chunk ^= (row>>1)&3 ->
// 16 lanes spread over 8 bank-quad positions = 2/quad = free (m136).
// Verified 0 conflicts in rounds 2-5.
#define SWZ(r)   (((r) >> 1) & 3)

typedef _Float16 f16x8  __attribute__((ext_vector_type(8)));
typedef float    f32x4  __attribute__((ext_vector_type(4)));

static __device__ __forceinline__ unsigned short f2h_bits(float f) {
  _Float16 h = (_Float16)f;
  return __builtin_bit_cast(unsigned short, h);
}

// async 16B/lane global->LDS copy; LDS dest is wave-uniform base + lane*16
static __device__ __forceinline__ void gl_lds16(const unsigned short* g, unsigned short* l) {
  __builtin_amdgcn_global_load_lds(
      (const __attribute__((address_space(1))) unsigned int*)g,
      (__attribute__((address_space(3))) unsigned int*)l, 16, 0, 0);
}

// ---- kernel 1: fused prep (A path + W path) — UNCHANGED --------------------
__global__ __launch_bounds__(256) void prep_k(const float* __restrict__ x,
                                              const float* __restrict__ coeffs,
                                              const float* __restrict__ bw,
                                              const float* __restrict__ gsl,
                                              const float* __restrict__ gstart,
                                              const float* __restrict__ rsp,
                                              unsigned short* __restrict__ A,
                                              unsigned short* __restrict__ W,
                                              float* __restrict__ out) {
  const int blk = blockIdx.x;
  if (blk < NBLK_A) {
    const int i  = (blk & 3) * 256 + threadIdx.x;
    const int b0 = (blk >> 2) * 16;
    const float rs = rsp[0];
    float g[NK];
    float acc = gstart[i];
    g[0] = acc;
#pragma unroll
    for (int t = 0; t < NK - 1; ++t) {
      float v  = gsl[i * (NK - 1) + t];
      float sp = (v > 20.f) ? v : log1pf(expf(v));  // softplus
      acc += sp;
      g[t + 1] = acc;
    }
    float r[30];
#pragma unroll
    for (int j = 0; j < 11; ++j) r[j]      = 1.f / (g[j + 1] - g[j] + EPS);
#pragma unroll
    for (int j = 0; j < 10; ++j) r[11 + j] = 1.f / (g[j + 2] - g[j] + EPS);
#pragma unroll
    for (int j = 0; j <  9; ++j) r[21 + j] = 1.f / (g[j + 3] - g[j] + EPS);

#pragma unroll 4
    for (int bb = 0; bb < 16; ++bb) {
      const int b = b0 + bb;
      float xv = x[(size_t)b * IN_DIM + i];
      float bas[NK - 1];
#pragma unroll
      for (int k = 0; k < NK - 1; ++k)
        bas[k] = (xv >= g[k] && xv < g[k + 1]) ? 1.f : 0.f;
      const int off[3] = {0, 11, 21};
#pragma unroll
      for (int d = 1; d <= 3; ++d) {
#pragma unroll
        for (int k = 0; k < NK - 1 - d; ++k) {
          float left  = (xv - g[k])         * r[off[d - 1] + k];
          float right = (g[k + d + 1] - xv) * r[off[d - 1] + k + 1];
          bas[k] = left * bas[k] + right * bas[k + 1];
        }
      }
      uint4 pack;
      pack.x = (unsigned)f2h_bits(bas[0]) | ((unsigned)f2h_bits(bas[1]) << 16);
      pack.y = (unsigned)f2h_bits(bas[2]) | ((unsigned)f2h_bits(bas[3]) << 16);
      pack.z = (unsigned)f2h_bits(bas[4]) | ((unsigned)f2h_bits(bas[5]) << 16);
      pack.w = (unsigned)f2h_bits(bas[6]) | ((unsigned)f2h_bits(bas[7]) << 16);
      *(uint4*)&A[(size_t)b * KDIM + i * NC] = pack;
      float s = xv / (1.f + expf(-xv));  // silu
      A[(size_t)b * KDIM + KSPLINE + i] = f2h_bits(s);
      out[(size_t)b * OUT_DIM + i] = rs * xv;  // init for gemm's += epilogue
    }
  } else {
    int idx = (blk - NBLK_A) * 256 + threadIdx.x;
    int n  = idx / (KDIM / 4);
    int k4 = (idx - n * (KDIM / 4)) * 4;
    float4 v;
    if (k4 < KSPLINE) v = *(const float4*)&coeffs[(size_t)n * KSPLINE + k4];
    else              v = *(const float4*)&bw[(size_t)n * IN_DIM + (k4 - KSPLINE)];
    ushort4 o;
    o.x = f2h_bits(v.x); o.y = f2h_bits(v.y); o.z = f2h_bits(v.z); o.w = f2h_bits(v.w);
    *(ushort4*)&W[(size_t)n * KDIM + k4] = o;
  }
}

// ---- kernel 2: 256x256 tile, wave 128x64, R4-proven ring, KSPLIT=4 ---------
// 8 waves (2M x 4N), wave-tile 128x64 = 8x4 grid of 16x16, mfma 16x16x32_f16.
// Per K32-tile per wave: 12 ds_read_b128 (A:8 + B:4) feed 32 MFMA — the m201
// balance point. 4-slot LDS ring (As 64KB + Bs 64KB = 128KB, 1 block/CU);
// iter u stages tile u+3 into slot (u+3)&3 = (u-1)&3 (tile u-1's reads all
// retired before its MFMA cluster -> before the iter-(u-1) barrier). Counted
// vmcnt (T4): 4 gl_lds/STAGE; steady vmcnt(8) = 2 tiles in flight; tail
// 8 -> 4 -> 0. ONE barrier per K-tile (R4==R5 showed phase-splitting neutral).
__global__ __launch_bounds__(512, 1) void gemm_k(const unsigned short* __restrict__ A,
                                                 const unsigned short* __restrict__ W,
                                                 float* __restrict__ out,
                                                 float* __restrict__ P,
                                                 int use_partial) {
  __shared__ __align__(16) unsigned short As[4][BM][BKQ];  // 64 KB
  __shared__ __align__(16) unsigned short Bs[4][BN][BKQ];  // 64 KB
  const int tid  = threadIdx.x;
  const int wave = tid >> 6;
  const int lane = tid & 63;

  // T1: XCD decode (256 % 8 == 0 -> bijective). Each XCD: pairs share a ks,
  // 2 bn x 16 bm -> W-slice 2x256x2304x2B = 2.36 MB L2-resident; A (75.5 MB)
  // streams through L3.
  const int s  = (blockIdx.x & 7) * 32 + (blockIdx.x >> 3);
  const int ks = s >> 6;                     // 0..3
  const int bn = (s >> 4) & 3;               // 0..3
  const int bm = s & 15;                     // 0..15

  // staging: thread -> row tid>>2 (0..127), 16B chunk tid&3; source chunk
  // pre-XOR'd by the read-side involution (rule #21). SWZ(r+128)==SWZ(r).
  const int srow = tid >> 2;
  const int scsw = ((tid & 3) ^ SWZ(srow)) * 8;
  const unsigned short* aG = A + (size_t)(bm * BM + srow) * KDIM + (size_t)ks * KPS + scsw;
  const unsigned short* bG = W + (size_t)(bn * BN + srow) * KDIM + (size_t)ks * KPS + scsw;

#define STAGE(t) do {                                                          \
    const int sl_ = (t) & 3; const int kb_ = (t) * BKQ;                        \
    gl_lds16(aG + kb_,                      &As[sl_][wave * 16][0]);           \
    gl_lds16(aG + (size_t)128 * KDIM + kb_, &As[sl_][128 + wave * 16][0]);     \
    gl_lds16(bG + kb_,                      &Bs[sl_][wave * 16][0]);           \
    gl_lds16(bG + (size_t)128 * KDIM + kb_, &Bs[sl_][128 + wave * 16][0]);     \
  } while (0)

  // fragment map (16x16x32): row = lane&15, k-chunk kg = lane>>4 (8 halfs)
  const int l15 = lane & 15;
  const int kg  = lane >> 4;
  const int wm  = (wave >> 2) * 128;    // 2 M-wave groups
  const int wn  = (wave & 3) * 64;      // 4 N-wave groups

  f32x4 acc[8][4] = {};

  // prologue: tiles 0,1,2 in flight (12 loads/thread); vmcnt(8) -> tile 0
  // landed; barrier publishes all waves' tile-0 stages.
  STAGE(0); STAGE(1); STAGE(2);
  asm volatile("s_waitcnt vmcnt(8)" ::: "memory");
  __builtin_amdgcn_s_barrier();

#pragma unroll 4
  for (int kt = 0; kt < NKT; ++kt) {
    const unsigned short* as = &As[kt & 3][0][0];
    const unsigned short* bs = &Bs[kt & 3][0][0];
    f16x8 af[8], bf[4];
#pragma unroll
    for (int mt = 0; mt < 8; ++mt) {
      int row = wm + mt * 16 + l15;
      af[mt] = *(const f16x8*)&as[row * BKQ + ((kg ^ SWZ(row)) * 8)];
    }
#pragma unroll
    for (int nt = 0; nt < 4; ++nt) {
      int row = wn + nt * 16 + l15;
      bf[nt] = *(const f16x8*)&bs[row * BKQ + ((kg ^ SWZ(row)) * 8)];
    }
    if (kt < NKT - 3) STAGE(kt + 3);     // issue-early; lands in ~3 iters
    __builtin_amdgcn_s_setprio(1);
#pragma unroll
    for (int mt = 0; mt < 8; ++mt)
#pragma unroll
      for (int nt = 0; nt < 4; ++nt)
        acc[mt][nt] = __builtin_amdgcn_mfma_f32_16x16x32_f16(af[mt], bf[nt], acc[mt][nt], 0, 0, 0);
    __builtin_amdgcn_s_setprio(0);
    // counted vmcnt BEFORE the slot-transition barrier: tile kt+1 resident
    // for everyone after the barrier; 2 tiles (8 loads) stay in flight.
    if (kt < NKT - 3)       asm volatile("s_waitcnt vmcnt(8)" ::: "memory");
    else if (kt == NKT - 3) asm volatile("s_waitcnt vmcnt(4)" ::: "memory");
    else if (kt == NKT - 2) asm volatile("s_waitcnt vmcnt(0)" ::: "memory");
    if (kt < NKT - 1) __builtin_amdgcn_s_barrier();
  }
#undef STAGE

  // epilogue: C/D 16x16 layout col=lane&15, row=(lane>>4)*4+reg (m89-verified)
  float* Pk = P + (size_t)(ks - 1) * BATCH * OUT_DIM;
#pragma unroll
  for (int mt = 0; mt < 8; ++mt) {
#pragma unroll
    for (int reg = 0; reg < 4; ++reg) {
      const int row = bm * BM + wm + mt * 16 + kg * 4 + reg;
      const size_t ro = (size_t)row * OUT_DIM;
#pragma unroll
      for (int nt = 0; nt < 4; ++nt) {
        const int col = bn * BN + wn + nt * 16 + l15;
        const float v = acc[mt][nt][reg];
        if (use_partial) {
          if (ks == 0) out[ro + col] += v;   // exclusive owner of slice 0
          else         Pk[ro + col]   = v;   // plain store, folded by reduce_k
        } else {
          atomicAdd(&out[ro + col], v);      // ws-too-small fallback
        }
      }
    }
  }
}

// ---- kernel 3: out += P0 + P1 + P2 (K-split fold, ~84 MB -> ~13 us) --------
__global__ __launch_bounds__(256) void reduce_k(float* __restrict__ out,
                                                const float* __restrict__ P) {
  const int n4 = (BATCH * OUT_DIM) / 4;      // 1,048,576 float4s
  const float4* P0 = (const float4*)P;
  const float4* P1 = P0 + n4;
  const float4* P2 = P1 + n4;
  for (int i = blockIdx.x * 256 + threadIdx.x; i < n4; i += gridDim.x * 256) {
    float4 o = ((const float4*)out)[i];
    float4 a = P0[i], b = P1[i], c = P2[i];
    o.x += a.x + b.x + c.x;
    o.y += a.y + b.y + c.y;
    o.z += a.z + b.z + c.z;
    o.w += a.w + b.w + c.w;
    ((float4*)out)[i] = o;
  }
}

// ---- host-side launch ------------------------------------------------------
extern "C" void kernel_launch(void* const* d_in, const int* in_sizes, int n_in,
                              void* d_out, int out_size, void* d_ws, size_t ws_size,
                              hipStream_t stream) {
  const float* x      = (const float*)d_in[0];  // (4096, 1024) fp32
  const float* coeffs = (const float*)d_in[1];  // (1024, 8192)
  const float* bw     = (const float*)d_in[2];  // (1024, 1024)
  const float* gsl    = (const float*)d_in[3];  // (1024, 11)
  const float* gstart = (const float*)d_in[4];  // (1024, 1)
  const float* rsp    = (const float*)d_in[5];  // (1,)

  // ws layout: A (75.5 MB f16) | W (18.9 MB f16) | P0-2 (50.3 MB f32) = 144.7 MB
  const size_t szA = (size_t)BATCH * KDIM * 2;
  const size_t szW = (size_t)OUT_DIM * KDIM * 2;
  const size_t szP = (size_t)BATCH * OUT_DIM * 4 * (KSPLIT - 1);
  char* ws = (char*)d_ws;
  unsigned short* A  = (unsigned short*)ws;
  unsigned short* W  = (unsigned short*)(ws + szA);
  float*          P  = (float*)(ws + szA + szW);
  float*          out = (float*)d_out;
  const int use_partial = (ws_size >= szA + szW + szP) ? 1 : 0;

  prep_k<<<NBLK_A + NBLK_W, 256, 0, stream>>>(x, coeffs, bw, gsl, gstart, rsp, A, W, out);
  gemm_k<<<NGBLK, 512, 0, stream>>>(A, W, out, P, use_partial);
  if (use_partial) reduce_k<<<2048, 256, 0, stream>>>(out, P);
}